// Round 13
// baseline (1614.475 us; speedup 1.0000x reference)
//
#include <hip/hip_runtime.h>

#define HN   128
#define NPG  32
#define NT   1024
#define NWAV 16    // waves per block; each wave owns 2 graphs
#define SPP  4     // graph-pairs per wave (serial)

typedef float f4 __attribute__((ext_vector_type(4)));
typedef float f2 __attribute__((ext_vector_type(2)));

__device__ __forceinline__ float tanh_fast(float v) {
  // tanh(v) = 1 - 2/(1+exp(2v)); saturates gracefully at +-1
  return 1.0f - 2.0f / (1.0f + __expf(2.0f * v));
}

__global__ __launch_bounds__(NT, 1) void gib_main(
    const float* __restrict__ x,  const float* __restrict__ W1,
    const float* __restrict__ b1, const float* __restrict__ W2,
    const float* __restrict__ b2, const float* __restrict__ gn,
    const float* __restrict__ un, const int* __restrict__ ei,
    float* __restrict__ out, float* __restrict__ ws,
    int G, long E, int epg)
{
  const int t  = threadIdx.x;
  const int wv = t >> 6;    // wave 0..15
  const int l  = t & 63;
  const int gh = l >> 5;    // graph within pair
  const int n  = l & 31;    // this lane's node

  __shared__ float s_lp[NWAV][2][NPG];
  __shared__ float s_a0[NWAV][2][NPG];

  const long GL  = (long)G * HN;
  const float b20 = b2[0], b21 = b2[1];

  const long pr0 = ((long)blockIdx.x * NWAV + wv) * SPP;

  for (int si = 0; si < SPP; ++si) {
    const long pr = pr0 + si;
    if (2 * pr >= G) break;              // wave-uniform exit
    const long g = 2 * pr + gh;
    if (g < G) {
      const long nb = g * NPG;
      const float* xrow = x + (nb + n) * HN;   // lane's node row
      const float* xgg  = x + nb * HN;
      const float* ug   = un + nb * HN;

      // ---- load lane's full x row into registers (read x ONCE for the MLP) ----
      f4 row[32];
      #pragma unroll
      for (int r = 0; r < 32; ++r) row[r] = *(const f4*)(xrow + 4 * r);

      // ================= MLP: 4 passes of 32 cols, all operands reg/SGPR ======
      float z0 = 0.f, z1 = 0.f;
      #pragma unroll
      for (int p = 0; p < 4; ++p) {
        const int c0 = p * 32;
        const float* w2p = W2 + c0 * 2;
        f4 acc[8];
        #pragma unroll
        for (int j = 0; j < 8; ++j) {          // b1: wave-uniform loads
          const float* bp = b1 + c0 + 4 * j;
          acc[j][0] = bp[0]; acc[j][1] = bp[1];
          acc[j][2] = bp[2]; acc[j][3] = bp[3];
        }
        #pragma unroll
        for (int k4 = 0; k4 < 32; ++k4) {
          #pragma unroll
          for (int kk = 0; kk < 4; ++kk) {
            const float* wr = W1 + (4 * k4 + kk) * HN + c0;  // wave-uniform (SMEM)
            const float xk = row[k4][kk];
            #pragma unroll
            for (int j = 0; j < 8; ++j) {
              acc[j][0] = fmaf(wr[4*j+0], xk, acc[j][0]);
              acc[j][1] = fmaf(wr[4*j+1], xk, acc[j][1]);
              acc[j][2] = fmaf(wr[4*j+2], xk, acc[j][2]);
              acc[j][3] = fmaf(wr[4*j+3], xk, acc[j][3]);
            }
          }
        }
        #pragma unroll
        for (int j = 0; j < 8; ++j) {
          #pragma unroll
          for (int m = 0; m < 4; ++m) {
            float h = tanh_fast(acc[j][m]);
            z0 = fmaf(h, w2p[(4*j+m)*2 + 0], z0);
            z1 = fmaf(h, w2p[(4*j+m)*2 + 1], z1);
          }
        }
      }

      // ================= softmax + gumbel (lane = its node) ==================
      float vSLN, vSLN2, vL2p, vpres;
      {
        float za = z0 + b20, zb = z1 + b21;
        float zm = fmaxf(za, zb);
        float e0 = __expf(za - zm), e1 = __expf(zb - zm);
        float a0 = e0 / (e0 + e1);
        f2 gnr = *(const f2*)(gn + (nb + n) * 2);
        float q0 = a0 + gnr[0], q1 = (1.f - a0) + gnr[1];
        float qm = fmaxf(q0, q1);
        float E0 = __expf(q0 - qm), E1 = __expf(q1 - qm);
        float lp = E0 / (E0 + E1), ln = 1.f - lp;
        s_lp[wv][gh][n] = lp;
        s_a0[wv][gh][n] = a0;
        out[2 * GL + nb + n] = (lp > 0.5f) ? 1.0f : 0.0f;   // active
        vSLN = ln; vSLN2 = ln * ln; vL2p = lp * lp; vpres = (a0 > 0.5f) ? 1.f : 0.f;
        #pragma unroll
        for (int m = 1; m <= 16; m <<= 1) {   // half-wave reduce
          vSLN  += __shfl_xor(vSLN,  m, 64);
          vSLN2 += __shfl_xor(vSLN2, m, 64);
          vL2p  += __shfl_xor(vL2p,  m, 64);
          vpres += __shfl_xor(vpres, m, 64);
        }
      }

      // ========== fused moments pass: S1,S2,A,Q1,Q2,B per feature ============
      // lane owns features {2n,2n+1} (half A) and {64+2n,65+2n} (half B)
      f2 S1a={0,0}, S2a={0,0}, Aa={0,0}, Q1a={0,0}, Q2a={0,0}, Ba={0,0};
      f2 S1b={0,0}, S2b={0,0}, Ab={0,0}, Q1b={0,0}, Q2b={0,0}, Bb={0,0};
      #pragma unroll 4
      for (int nd = 0; nd < NPG; ++nd) {
        f2 xa = *(const f2*)(xgg + nd * HN + 2 * n);
        f2 xb = *(const f2*)(xgg + nd * HN + 64 + 2 * n);
        f2 ua = *(const f2*)(ug  + nd * HN + 2 * n);
        f2 ub = *(const f2*)(ug  + nd * HN + 64 + 2 * n);
        float lpn = s_lp[wv][gh][nd];
        float lnn = 1.f - lpn;
        float lp2 = lpn * lpn;
        f2 ta = xa * xa, tb = xb * xb;
        S1a += xa; S1b += xb;
        S2a += ta; S2b += tb;
        Aa[0] = fmaf(lpn, xa[0], Aa[0]); Aa[1] = fmaf(lpn, xa[1], Aa[1]);
        Ab[0] = fmaf(lpn, xb[0], Ab[0]); Ab[1] = fmaf(lpn, xb[1], Ab[1]);
        Q1a[0] = fmaf(lp2, xa[0], Q1a[0]); Q1a[1] = fmaf(lp2, xa[1], Q1a[1]);
        Q1b[0] = fmaf(lp2, xb[0], Q1b[0]); Q1b[1] = fmaf(lp2, xb[1], Q1b[1]);
        Q2a[0] = fmaf(lp2, ta[0], Q2a[0]); Q2a[1] = fmaf(lp2, ta[1], Q2a[1]);
        Q2b[0] = fmaf(lp2, tb[0], Q2b[0]); Q2b[1] = fmaf(lp2, tb[1], Q2b[1]);
        Ba[0] = fmaf(lnn, ua[0], Ba[0]); Ba[1] = fmaf(lnn, ua[1], Ba[1]);
        Bb[0] = fmaf(lnn, ub[0], Bb[0]); Bb[1] = fmaf(lnn, ub[1], Bb[1]);
      }

      // ---- finalize per-feature stats, graph_emb, noisy_emb, T2, r2 ----
      float tv = 0.f, rr = 0.f;
      {
        f2 ne;
        // half A
        {
          float m0 = S1a[0] * (1.f / NPG), m1 = S1a[1] * (1.f / NPG);
          float v0 = fmaxf((S2a[0] - S1a[0] * m0) * (1.f / (NPG - 1)), 0.f);
          float v1 = fmaxf((S2a[1] - S1a[1] * m1) * (1.f / (NPG - 1)), 0.f);
          float sd0 = sqrtf(v0), sd1 = sqrtf(v1);
          float in0 = 1.f / (sd0 + 1e-7f), in1 = 1.f / (sd1 + 1e-7f);
          float iv0 = in0 * in0, iv1 = in1 * in1;
          ne[0] = fmaf(m0, vSLN, Aa[0]) + sd0 * Ba[0];
          ne[1] = fmaf(m1, vSLN, Aa[1]) + sd1 * Ba[1];
          *(f2*)&out[GL + g * HN + 2 * n] = ne;          // noisy low
          *(f2*)&out[g * HN + 2 * n] = S1a;              // graph_emb low
          tv += iv0 * (Q2a[0] - 2.f * m0 * Q1a[0] + m0 * m0 * vL2p)
              + iv1 * (Q2a[1] - 2.f * m1 * Q1a[1] + m1 * m1 * vL2p);
          float r0 = sd0 * in0, r1 = sd1 * in1;
          rr += r0 * r0 + r1 * r1;
        }
        // half B
        {
          float m0 = S1b[0] * (1.f / NPG), m1 = S1b[1] * (1.f / NPG);
          float v0 = fmaxf((S2b[0] - S1b[0] * m0) * (1.f / (NPG - 1)), 0.f);
          float v1 = fmaxf((S2b[1] - S1b[1] * m1) * (1.f / (NPG - 1)), 0.f);
          float sd0 = sqrtf(v0), sd1 = sqrtf(v1);
          float in0 = 1.f / (sd0 + 1e-7f), in1 = 1.f / (sd1 + 1e-7f);
          float iv0 = in0 * in0, iv1 = in1 * in1;
          ne[0] = fmaf(m0, vSLN, Ab[0]) + sd0 * Bb[0];
          ne[1] = fmaf(m1, vSLN, Ab[1]) + sd1 * Bb[1];
          *(f2*)&out[GL + g * HN + 64 + 2 * n] = ne;     // noisy high
          *(f2*)&out[g * HN + 64 + 2 * n] = S1b;         // graph_emb high
          tv += iv0 * (Q2b[0] - 2.f * m0 * Q1b[0] + m0 * m0 * vL2p)
              + iv1 * (Q2b[1] - 2.f * m1 * Q1b[1] + m1 * m1 * vL2p);
          float r0 = sd0 * in0, r1 = sd1 * in1;
          rr += r0 * r0 + r1 * r1;
        }
        #pragma unroll
        for (int m = 1; m <= 16; m <<= 1) {
          tv += __shfl_xor(tv, m, 64);
          rr += __shfl_xor(rr, m, 64);
        }
      }

      // ================= edges -> 2x2 adjacency; per-graph scalars ===========
      {
        float c00 = 0.f, c01 = 0.f, c10 = 0.f, c11 = 0.f;
        for (int e = n; e < epg; e += NPG) {
          int s2 = ei[g * epg + e] - (int)nb;
          int d2 = ei[E + g * epg + e] - (int)nb;
          float as0 = s_a0[wv][gh][s2], as1 = 1.f - as0;
          float ad0 = s_a0[wv][gh][d2], ad1 = 1.f - ad0;
          c00 = fmaf(as0, ad0, c00); c01 = fmaf(as0, ad1, c01);
          c10 = fmaf(as1, ad0, c10); c11 = fmaf(as1, ad1, c11);
        }
        #pragma unroll
        for (int m = 1; m <= 16; m <<= 1) {
          c00 += __shfl_xor(c00, m, 64); c01 += __shfl_xor(c01, m, 64);
          c10 += __shfl_xor(c10, m, 64); c11 += __shfl_xor(c11, m, 64);
        }
        if (n == 0) {
          float d0 = c00 / fmaxf(fabsf(c00) + fabsf(c01), 1e-12f);
          float d1 = c11 / fmaxf(fabsf(c10) + fabsf(c11), 1e-12f);
          float pen = 0.5f * ((d0 - 1.f) * (d0 - 1.f) + (d1 - 1.f) * (d1 - 1.f));
          float kl = (0.5f * vSLN2 * rr + (float)NPG * tv) / (float)(NPG * HN);
          ws[g]                 = kl;
          ws[(size_t)G + g]     = pen;
          ws[2 * (size_t)G + g] = vpres * (1.0f / NPG);
        }
      }
    }
  }
}

// deterministic fixed-order reduction of the 3 per-graph scalar arrays
__global__ __launch_bounds__(1024) void gib_final(const float* __restrict__ ws,
                                                  float* __restrict__ out,
                                                  int G, long base)
{
  __shared__ float red[3][16];
  const int t = threadIdx.x, w = t >> 6, lid = t & 63;
  float s0 = 0.f, s1 = 0.f, s2 = 0.f;
  for (int i = t; i < G; i += 1024) {
    s0 += ws[(size_t)G + i];       // pos_penalty
    s1 += ws[i];                   // kl
    s2 += ws[2 * (size_t)G + i];   // preserve
  }
  #pragma unroll
  for (int m = 1; m <= 32; m <<= 1) {
    s0 += __shfl_xor(s0, m, 64);
    s1 += __shfl_xor(s1, m, 64);
    s2 += __shfl_xor(s2, m, 64);
  }
  if (lid == 0) { red[0][w] = s0; red[1][w] = s1; red[2][w] = s2; }
  __syncthreads();
  if (t == 0) {
    float r0 = 0.f, r1 = 0.f, r2 = 0.f;
    for (int i = 0; i < 16; ++i) { r0 += red[0][i]; r1 += red[1][i]; r2 += red[2][i]; }
    out[base + 0] = r0 / (float)G;
    out[base + 1] = r1 / (float)G;
    out[base + 2] = r2 / (float)G;
  }
}

extern "C" void kernel_launch(void* const* d_in, const int* in_sizes, int n_in,
                              void* d_out, int out_size, void* d_ws, size_t ws_size,
                              hipStream_t stream)
{
  const float* x  = (const float*)d_in[0];
  const float* W1 = (const float*)d_in[1];
  const float* b1 = (const float*)d_in[2];
  const float* W2 = (const float*)d_in[3];
  const float* b2 = (const float*)d_in[4];
  const float* gn = (const float*)d_in[5];
  const float* un = (const float*)d_in[6];
  const int*   ei = (const int*)d_in[7];
  float* out = (float*)d_out;
  float* ws  = (float*)d_ws;

  const long N = (long)in_sizes[0] / HN;
  const int  G = (int)(N / NPG);
  const long E = (long)in_sizes[7] / 2;
  const int epg = (int)(E / G);

  const long graphsPerBlock = 2L * NWAV * SPP;   // 128
  const int nblocks = (int)((G + graphsPerBlock - 1) / graphsPerBlock);   // 256
  hipLaunchKernelGGL(gib_main, dim3(nblocks), dim3(NT), 0, stream,
                     x, W1, b1, W2, b2, gn, un, ei, out, ws, G, E, epg);
  const long base = 2L * (long)G * HN + N;
  hipLaunchKernelGGL(gib_final, dim3(1), dim3(1024), 0, stream, ws, out, G, base);
}